// Round 7
// baseline (3884.732 us; speedup 1.0000x reference)
//
#include <hip/hip_runtime.h>
#include <hip/hip_bf16.h>

#define N_NODES 100000
#define N_EDGES 3200000
#define N_GRAPHS 256
#define D_IN 320
#define D_H 64

#define NBIN 391                    // ceil(N_NODES / 256) bins of 256 dst nodes
#define BIN_CAP 12288               // mean bin load 8186, sigma~90 -> +45 sigma
#define HIST_BLOCKS 256
#define HIST_CHUNK ((N_EDGES + HIST_BLOCKS - 1) / HIST_BLOCKS)
#define PART_BLOCKS 200
#define PART_CHUNK ((N_EDGES + PART_BLOCKS - 1) / PART_BLOCKS)   // 16000

#define NKB 13                      // src buckets of 8192 nodes (2 MB of u, fits XCD L2)

// ---------------- CSR build (block-private chunk partition) ----------------

__global__ __launch_bounds__(256) void k_hist(const int* __restrict__ dst,
                                              int* __restrict__ ghist) {
    __shared__ int lh[NBIN];
    for (int i = threadIdx.x; i < NBIN; i += 256) lh[i] = 0;
    __syncthreads();
    int beg = blockIdx.x * HIST_CHUNK;
    int end = min(beg + HIST_CHUNK, N_EDGES);
    for (int e = beg + threadIdx.x; e < end; e += 256)
        atomicAdd(&lh[dst[e] >> 8], 1);
    __syncthreads();
    for (int i = threadIdx.x; i < NBIN; i += 256)
        if (lh[i]) atomicAdd(&ghist[i], lh[i]);
}

__global__ __launch_bounds__(512) void k_scanbins(const int* __restrict__ ghist,
                                                  int* __restrict__ binbase,
                                                  int* __restrict__ gcur) {
    __shared__ int sa[512], sb[512];
    int t = threadIdx.x;
    int v = (t < NBIN) ? ghist[t] : 0;
    sa[t] = v;
    __syncthreads();
    int* in = sa; int* out = sb;
    for (int off = 1; off < 512; off <<= 1) {
        out[t] = in[t] + (t >= off ? in[t - off] : 0);
        __syncthreads();
        int* tmp = in; in = out; out = tmp;
    }
    int excl = in[t] - v;
    if (t < NBIN) { binbase[t] = excl; gcur[t] = excl; }
    if (t == 511) binbase[NBIN] = in[511];
}

// partition edges into 391 bins; each block reserves a private contiguous
// chunk per bin (one global atomic per (block,bin)).
__global__ __launch_bounds__(256) void k_part(const int* __restrict__ src,
                                              const int* __restrict__ dst,
                                              int* __restrict__ gcur,
                                              int* __restrict__ ebuf) {
    __shared__ int lh[NBIN], gb[NBIN], cur[NBIN];
    for (int i = threadIdx.x; i < NBIN; i += 256) { lh[i] = 0; cur[i] = 0; }
    __syncthreads();
    int beg = blockIdx.x * PART_CHUNK;
    int end = min(beg + PART_CHUNK, N_EDGES);
    for (int e = beg + threadIdx.x; e < end; e += 256)
        atomicAdd(&lh[dst[e] >> 8], 1);
    __syncthreads();
    for (int i = threadIdx.x; i < NBIN; i += 256)
        gb[i] = lh[i] ? atomicAdd(&gcur[i], lh[i]) : 0;
    __syncthreads();
    for (int e = beg + threadIdx.x; e < end; e += 256) {
        int d = dst[e], s = src[e];
        int bin = d >> 8;
        int r = atomicAdd(&cur[bin], 1);
        ebuf[gb[bin] + r] = ((d & 255) << 17) | s;   // dst-low-8 | src(17b)
    }
}

// one block per bin: counting-sort by (src_bucket, dst_local) -- bucket-MAJOR.
// Emits: col packed as (dst_local<<17|src), rp3[bin][k*4+g] boundaries
// (start of bucket k, 64-node group g), and dinv.
__global__ __launch_bounds__(256) void k_sortbin(const int* __restrict__ binbase,
                                                 const int* __restrict__ ebuf,
                                                 int* __restrict__ col,
                                                 int* __restrict__ rp3,
                                                 float* __restrict__ dinv) {
    __shared__ int hc[4096], sc[4096];
    __shared__ int sa[256], sb[256];
    __shared__ int scol[BIN_CAP];
    int b = blockIdx.x, t = threadIdx.x;
    int e0 = binbase[b], e1 = binbase[b + 1];
    for (int i = t; i < 4096; i += 256) hc[i] = 0;
    __syncthreads();
    for (int i = e0 + t; i < e1; i += 256) {
        int pk = ebuf[i];
        int dl = pk >> 17, s = pk & 0x1FFFF;
        atomicAdd(&hc[((s >> 13) << 8) | dl], 1);   // key = bucket*256 + dl
    }
    __syncthreads();
    int loc[16]; int sum = 0;
#pragma unroll
    for (int q = 0; q < 16; ++q) { loc[q] = sum; sum += hc[t * 16 + q]; }
    sa[t] = sum;
    __syncthreads();
    int* in = sa; int* out = sb;
    for (int o = 1; o < 256; o <<= 1) {
        out[t] = in[t] + (t >= o ? in[t - o] : 0);
        __syncthreads();
        int* tm = in; in = out; out = tm;
    }
    int tbase = in[t] - sum;
#pragma unroll
    for (int q = 0; q < 16; ++q) sc[t * 16 + q] = tbase + loc[q];
    // rp3 boundaries: key j*64 is owned by thread t=4j, local key 0
    if ((t & 3) == 0 && (t >> 2) < NKB * 4) rp3[b * 53 + (t >> 2)] = e0 + tbase;
    if (t == 0) rp3[b * 53 + 52] = e1;
    // dinv from per-dl degree (dl = t)
    int node = (b << 8) + t;
    if (node < N_NODES) {
        int deg = 0;
#pragma unroll
        for (int k = 0; k < NKB; ++k) deg += hc[(k << 8) + t];
        dinv[node] = rsqrtf((float)(deg + 1));   // +1 self loop
    }
    __syncthreads();
    for (int i = e0 + t; i < e1; i += 256) {
        int pk = ebuf[i];
        int dl = pk >> 17, s = pk & 0x1FFFF;
        int p = atomicAdd(&sc[((s >> 13) << 8) | dl], 1);
        if (p < BIN_CAP) scol[p] = (dl << 17) | s;
    }
    __syncthreads();
    int n = e1 - e0;
    for (int i = t; i < n; i += 256) col[e0 + i] = scol[i];
}

// ---------------- tiled GEMM transform (layer 1: 320 -> 64) ----------------
template<int K>
__global__ __launch_bounds__(256) void k_gemm(const float* __restrict__ A,
                                              const float* __restrict__ W,
                                              const float* __restrict__ dinv,
                                              float* __restrict__ u) {
    __shared__ __align__(16) float xt[64][68];
    __shared__ __align__(16) float ws[64][68];
    int t = threadIdx.x;
    int ti = t & 15;
    int tj = t >> 4;
    int node0 = blockIdx.x * 64;
    float acc[4][4] = {{0.f}};

    for (int kc = 0; kc < K; kc += 64) {
        if (kc) __syncthreads();
#pragma unroll
        for (int p = 0; p < 4; ++p) {
            int m = tj + 16 * p;
            int node = node0 + m;
            if (node >= N_NODES) node = N_NODES - 1;
            float4 v = *(const float4*)(A + (size_t)node * K + kc + 4 * ti);
            xt[4 * ti + 0][m] = v.x;
            xt[4 * ti + 1][m] = v.y;
            xt[4 * ti + 2][m] = v.z;
            xt[4 * ti + 3][m] = v.w;
            float4 wv = *(const float4*)(W + (size_t)(kc + m) * D_H + 4 * ti);
            *(float4*)&ws[m][4 * ti] = wv;
        }
        __syncthreads();
#pragma unroll 16
        for (int k = 0; k < 64; ++k) {
            float4 xv = *(const float4*)&xt[k][4 * tj];
            float4 wv = *(const float4*)&ws[k][4 * ti];
            float xa[4] = {xv.x, xv.y, xv.z, xv.w};
            float wa[4] = {wv.x, wv.y, wv.z, wv.w};
#pragma unroll
            for (int i = 0; i < 4; ++i)
#pragma unroll
                for (int j = 0; j < 4; ++j)
                    acc[i][j] = fmaf(xa[i], wa[j], acc[i][j]);
        }
    }
#pragma unroll
    for (int i = 0; i < 4; ++i) {
        int node = node0 + 4 * tj + i;
        if (node < N_NODES) {
            float dv = dinv[node];
            float4 o = make_float4(acc[i][0] * dv, acc[i][1] * dv,
                                   acc[i][2] * dv, acc[i][3] * dv);
            *(float4*)(u + (size_t)node * D_H + 4 * ti) = o;
        }
    }
}

// ---------------- fused bucket-phased aggregation ----------------
// Block = 256 threads, 64 dst nodes, 16 KB LDS accumulator. 1564 blocks all
// co-resident (~6/CU, ~24 waves/CU). Per bucket the 4 waves edge-parallel
// split the group's contiguous range with an 8-deep gather pipeline.

__device__ __forceinline__ void grp_gather(const float* __restrict__ uin,
                                           const int* __restrict__ rg,
                                           const int* __restrict__ col,
                                           float (*hacc)[64],
                                           int g, int w, int lane) {
    for (int k = 0; k < NKB; ++k) {
        int beg = rg[k * 4 + g], end = rg[k * 4 + g + 1];
        int n = end - beg, per = (n + 3) >> 2;
        int e = beg + w * per;
        int we = min(e + per, end);
        for (; e + 7 < we; e += 8) {
            int p0 = col[e],     p1 = col[e + 1], p2 = col[e + 2], p3 = col[e + 3];
            int p4 = col[e + 4], p5 = col[e + 5], p6 = col[e + 6], p7 = col[e + 7];
            float v0 = uin[(size_t)(p0 & 0x1FFFF) * D_H + lane];
            float v1 = uin[(size_t)(p1 & 0x1FFFF) * D_H + lane];
            float v2 = uin[(size_t)(p2 & 0x1FFFF) * D_H + lane];
            float v3 = uin[(size_t)(p3 & 0x1FFFF) * D_H + lane];
            float v4 = uin[(size_t)(p4 & 0x1FFFF) * D_H + lane];
            float v5 = uin[(size_t)(p5 & 0x1FFFF) * D_H + lane];
            float v6 = uin[(size_t)(p6 & 0x1FFFF) * D_H + lane];
            float v7 = uin[(size_t)(p7 & 0x1FFFF) * D_H + lane];
            atomicAdd(&hacc[(p0 >> 17) & 63][lane], v0);
            atomicAdd(&hacc[(p1 >> 17) & 63][lane], v1);
            atomicAdd(&hacc[(p2 >> 17) & 63][lane], v2);
            atomicAdd(&hacc[(p3 >> 17) & 63][lane], v3);
            atomicAdd(&hacc[(p4 >> 17) & 63][lane], v4);
            atomicAdd(&hacc[(p5 >> 17) & 63][lane], v5);
            atomicAdd(&hacc[(p6 >> 17) & 63][lane], v6);
            atomicAdd(&hacc[(p7 >> 17) & 63][lane], v7);
        }
        for (; e < we; ++e) {
            int pk = col[e];
            atomicAdd(&hacc[(pk >> 17) & 63][lane],
                      uin[(size_t)(pk & 0x1FFFF) * D_H + lane]);
        }
        __syncthreads();
    }
}

// agg(uin) -> +self -> *dinv -> +b -> relu -> @W -> *dinv -> uout
__global__ __launch_bounds__(256) void k_fagg(const float* __restrict__ uin,
                                              const int* __restrict__ rp3,
                                              const int* __restrict__ col,
                                              const float* __restrict__ dinv,
                                              const float* __restrict__ b,
                                              const float* __restrict__ W,
                                              float* __restrict__ uout) {
    __shared__ float hacc[64][64];
    int t = threadIdx.x, w = t >> 6, lane = t & 63;
    int bin = blockIdx.x >> 2, g = blockIdx.x & 3;
    int nbase = (bin << 8) + (g << 6);
    for (int i = t; i < 64 * 16; i += 256) ((float4*)hacc)[i] = make_float4(0, 0, 0, 0);
    __syncthreads();
    grp_gather(uin, rp3 + bin * 53, col, hacc, g, w, lane);
    float bl_ = b[lane];
    for (int s = 0; s < 16; ++s) {
        int nl = (w << 4) + s, node = nbase + nl;
        if (node >= N_NODES) break;
        float dv = dinv[node];
        float hv = (hacc[nl][lane] + uin[(size_t)node * D_H + lane]) * dv + bl_;
        hv = fmaxf(hv, 0.f);
        float acc = 0.f;
#pragma unroll
        for (int kk = 0; kk < 64; ++kk)
            acc = fmaf(__shfl(hv, kk, 64), W[kk * D_H + lane], acc);
        uout[(size_t)node * D_H + lane] = acc * dv;
    }
}

// agg(uin) -> +self -> *dinv -> +b3 -> dot(Wl) -> val
__global__ __launch_bounds__(256) void k_fagg_dot(const float* __restrict__ uin,
                                                  const int* __restrict__ rp3,
                                                  const int* __restrict__ col,
                                                  const float* __restrict__ dinv,
                                                  const float* __restrict__ b,
                                                  const float* __restrict__ Wl,
                                                  float* __restrict__ val) {
    __shared__ float hacc[64][64];
    int t = threadIdx.x, w = t >> 6, lane = t & 63;
    int bin = blockIdx.x >> 2, g = blockIdx.x & 3;
    int nbase = (bin << 8) + (g << 6);
    for (int i = t; i < 64 * 16; i += 256) ((float4*)hacc)[i] = make_float4(0, 0, 0, 0);
    __syncthreads();
    grp_gather(uin, rp3 + bin * 53, col, hacc, g, w, lane);
    float bl_ = b[lane], wl = Wl[lane];
    for (int s = 0; s < 16; ++s) {
        int nl = (w << 4) + s, node = nbase + nl;
        if (node >= N_NODES) break;
        float hv = (hacc[nl][lane] + uin[(size_t)node * D_H + lane]) * dinv[node] + bl_;
        float v = hv * wl;
#pragma unroll
        for (int m = 32; m > 0; m >>= 1) v += __shfl_xor(v, m, 64);
        if (lane == 0) val[node] = v;
    }
}

// one block per graph: batch is sorted, binary-search the segment, reduce.
__global__ __launch_bounds__(256) void k_gpool(const float* __restrict__ val,
                                               const int* __restrict__ batch,
                                               const float* __restrict__ bl,
                                               float* __restrict__ out) {
    int g = blockIdx.x;
    int l = 0, r = N_NODES;
    while (l < r) { int m = (l + r) >> 1; if (batch[m] < g) l = m + 1; else r = m; }
    int lo = l;
    r = N_NODES;
    while (l < r) { int m = (l + r) >> 1; if (batch[m] < g + 1) l = m + 1; else r = m; }
    int hi = l;
    float s = 0.0f;
    for (int i = lo + threadIdx.x; i < hi; i += 256) s += val[i];
#pragma unroll
    for (int m = 32; m > 0; m >>= 1) s += __shfl_xor(s, m, 64);
    __shared__ float red[4];
    int wid = threadIdx.x >> 6, lane = threadIdx.x & 63;
    if (lane == 0) red[wid] = s;
    __syncthreads();
    if (threadIdx.x == 0) {
        float t = red[0] + red[1] + red[2] + red[3];
        out[g] = t / fmaxf((float)(hi - lo), 1.0f) + bl[0];
    }
}

// ---------------- launch ----------------

extern "C" void kernel_launch(void* const* d_in, const int* in_sizes, int n_in,
                              void* d_out, int out_size, void* d_ws, size_t ws_size,
                              hipStream_t stream) {
    const float* x   = (const float*)d_in[0];
    const int*   ei  = (const int*)d_in[1];
    const int*   bat = (const int*)d_in[2];
    const float* W1  = (const float*)d_in[3];
    const float* b1  = (const float*)d_in[4];
    const float* W2  = (const float*)d_in[5];
    const float* b2  = (const float*)d_in[6];
    const float* W3  = (const float*)d_in[7];
    const float* b3  = (const float*)d_in[8];
    const float* Wl  = (const float*)d_in[9];
    const float* bl  = (const float*)d_in[10];
    float* out = (float*)d_out;

    char* p = (char*)d_ws;
    auto alloc = [&](size_t bytes) -> void* {
        void* r = (void*)p;
        p += (bytes + 255) & ~(size_t)255;
        return r;
    };
    int*   ghist   = (int*)alloc((size_t)NBIN * 4);
    int*   binbase = (int*)alloc((size_t)(NBIN + 1) * 4);
    int*   gcur    = (int*)alloc((size_t)NBIN * 4);
    int*   rp3     = (int*)alloc((size_t)NBIN * 53 * 4);
    float* dinv    = (float*)alloc((size_t)N_NODES * 4);
    int*   colb    = (int*)alloc((size_t)N_EDGES * 4);
    int*   ebuf    = (int*)alloc((size_t)N_EDGES * 4);
    float* u1      = (float*)alloc((size_t)N_NODES * D_H * 4);
    float* u2      = (float*)alloc((size_t)N_NODES * D_H * 4);
    float* val     = (float*)alloc((size_t)N_NODES * 4);

    hipMemsetAsync(ghist, 0, (size_t)NBIN * 4, stream);

    const int* srcp = ei;
    const int* dstp = ei + N_EDGES;

    int gbl = (N_NODES + 63) / 64;

    // CSR build (bucket-major per-bin sort, rp3 boundaries)
    k_hist<<<HIST_BLOCKS, 256, 0, stream>>>(dstp, ghist);
    k_scanbins<<<1, 512, 0, stream>>>(ghist, binbase, gcur);
    k_part<<<PART_BLOCKS, 256, 0, stream>>>(srcp, dstp, gcur, ebuf);
    k_sortbin<<<NBIN, 256, 0, stream>>>(binbase, ebuf, colb, rp3, dinv);

    // layer 1 transform: 320 -> 64
    k_gemm<D_IN><<<gbl, 256, 0, stream>>>(x, W1, dinv, u1);
    // agg1 + relu + xform(W2)
    k_fagg<<<NBIN * 4, 256, 0, stream>>>(u1, rp3, colb, dinv, b1, W2, u2);
    // agg2 + relu + xform(W3)
    k_fagg<<<NBIN * 4, 256, 0, stream>>>(u2, rp3, colb, dinv, b2, W3, u1);
    // agg3 + head dot
    k_fagg_dot<<<NBIN * 4, 256, 0, stream>>>(u1, rp3, colb, dinv, b3, Wl, val);

    // pooling
    k_gpool<<<N_GRAPHS, 256, 0, stream>>>(val, bat, bl, out);
}

// Round 8
// 617.294 us; speedup vs baseline: 6.2932x; 6.2932x over previous
//
#include <hip/hip_runtime.h>
#include <hip/hip_bf16.h>

#define N_NODES 100000
#define N_EDGES 3200000
#define N_GRAPHS 256
#define D_IN 320
#define D_H 64

#define NBIN 391                    // ceil(N_NODES / 256) bins of 256 dst nodes
#define BIN_CAP 12288               // mean bin load 8186, sigma~90 -> +45 sigma
#define HIST_BLOCKS 256
#define HIST_CHUNK ((N_EDGES + HIST_BLOCKS - 1) / HIST_BLOCKS)
#define PART_BLOCKS 200
#define PART_CHUNK ((N_EDGES + PART_BLOCKS - 1) / PART_BLOCKS)   // 16000

// ---------------- CSR build (block-private chunk partition) ----------------

__global__ __launch_bounds__(256) void k_hist(const int* __restrict__ dst,
                                              int* __restrict__ ghist) {
    __shared__ int lh[NBIN];
    for (int i = threadIdx.x; i < NBIN; i += 256) lh[i] = 0;
    __syncthreads();
    int beg = blockIdx.x * HIST_CHUNK;
    int end = min(beg + HIST_CHUNK, N_EDGES);
    for (int e = beg + threadIdx.x; e < end; e += 256)
        atomicAdd(&lh[dst[e] >> 8], 1);
    __syncthreads();
    for (int i = threadIdx.x; i < NBIN; i += 256)
        if (lh[i]) atomicAdd(&ghist[i], lh[i]);
}

__global__ __launch_bounds__(512) void k_scanbins(const int* __restrict__ ghist,
                                                  int* __restrict__ binbase,
                                                  int* __restrict__ gcur,
                                                  int* __restrict__ rowptr) {
    __shared__ int sa[512], sb[512];
    int t = threadIdx.x;
    int v = (t < NBIN) ? ghist[t] : 0;
    sa[t] = v;
    __syncthreads();
    int* in = sa; int* out = sb;
    for (int off = 1; off < 512; off <<= 1) {
        out[t] = in[t] + (t >= off ? in[t - off] : 0);
        __syncthreads();
        int* tmp = in; in = out; out = tmp;
    }
    int excl = in[t] - v;
    if (t < NBIN) { binbase[t] = excl; gcur[t] = excl; }
    if (t == 511) { binbase[NBIN] = in[511]; rowptr[N_NODES] = in[511]; }
}

// partition edges into 391 bins; each block reserves a private contiguous
// chunk per bin (one global atomic per (block,bin)) -> every ebuf cacheline
// is written by exactly one block, once.
__global__ __launch_bounds__(256) void k_part(const int* __restrict__ src,
                                              const int* __restrict__ dst,
                                              int* __restrict__ gcur,
                                              int* __restrict__ ebuf) {
    __shared__ int lh[NBIN], gb[NBIN], cur[NBIN];
    for (int i = threadIdx.x; i < NBIN; i += 256) { lh[i] = 0; cur[i] = 0; }
    __syncthreads();
    int beg = blockIdx.x * PART_CHUNK;
    int end = min(beg + PART_CHUNK, N_EDGES);
    for (int e = beg + threadIdx.x; e < end; e += 256)
        atomicAdd(&lh[dst[e] >> 8], 1);
    __syncthreads();
    for (int i = threadIdx.x; i < NBIN; i += 256)
        gb[i] = lh[i] ? atomicAdd(&gcur[i], lh[i]) : 0;
    __syncthreads();
    for (int e = beg + threadIdx.x; e < end; e += 256) {
        int d = dst[e], s = src[e];
        int bin = d >> 8;
        int r = atomicAdd(&cur[bin], 1);
        ebuf[gb[bin] + r] = ((d & 255) << 17) | s;   // dst-low-8 | src(17b)
    }
}

// one block per bin: LDS counting-sort by dst; writes col coalesced and
// emits rowptr + dinv for its 256 nodes.
__global__ __launch_bounds__(256) void k_sortbin(const int* __restrict__ binbase,
                                                 const int* __restrict__ ebuf,
                                                 int* __restrict__ col,
                                                 int* __restrict__ rowptr,
                                                 float* __restrict__ dinv) {
    __shared__ int hc[256], sc[256], sa[256], sb[256];
    __shared__ int scol[BIN_CAP];
    int b = blockIdx.x, t = threadIdx.x;
    int d0 = b << 8;
    int e0 = binbase[b], e1 = binbase[b + 1];
    hc[t] = 0;
    __syncthreads();
    for (int i = e0 + t; i < e1; i += 256)
        atomicAdd(&hc[ebuf[i] >> 17], 1);
    __syncthreads();
    sa[t] = hc[t];
    __syncthreads();
    int* in = sa; int* out = sb;
    for (int o = 1; o < 256; o <<= 1) {
        out[t] = in[t] + (t >= o ? in[t - o] : 0);
        __syncthreads();
        int* tm = in; in = out; out = tm;
    }
    int excl = in[t] - hc[t];
    sc[t] = excl;
    int node = d0 + t;
    if (node < N_NODES) {
        rowptr[node] = e0 + excl;
        dinv[node] = rsqrtf((float)(hc[t] + 1));   // +1 self loop
    }
    __syncthreads();
    for (int i = e0 + t; i < e1; i += 256) {
        int pk = ebuf[i];
        int p = atomicAdd(&sc[pk >> 17], 1);
        if (p < BIN_CAP) scol[p] = pk & 0x1FFFF;
    }
    __syncthreads();
    int n = e1 - e0;
    for (int i = t; i < n; i += 256) col[e0 + i] = scol[i];
}

// ---------------- tiled GEMM transform (layer 1: 320 -> 64) ----------------
template<int K>
__global__ __launch_bounds__(256) void k_gemm(const float* __restrict__ A,
                                              const float* __restrict__ W,
                                              const float* __restrict__ dinv,
                                              float* __restrict__ u) {
    __shared__ __align__(16) float xt[64][68];
    __shared__ __align__(16) float ws[64][68];
    int t = threadIdx.x;
    int ti = t & 15;
    int tj = t >> 4;
    int node0 = blockIdx.x * 64;
    float acc[4][4] = {{0.f}};

    for (int kc = 0; kc < K; kc += 64) {
        if (kc) __syncthreads();
#pragma unroll
        for (int p = 0; p < 4; ++p) {
            int m = tj + 16 * p;
            int node = node0 + m;
            if (node >= N_NODES) node = N_NODES - 1;
            float4 v = *(const float4*)(A + (size_t)node * K + kc + 4 * ti);
            xt[4 * ti + 0][m] = v.x;
            xt[4 * ti + 1][m] = v.y;
            xt[4 * ti + 2][m] = v.z;
            xt[4 * ti + 3][m] = v.w;
            float4 wv = *(const float4*)(W + (size_t)(kc + m) * D_H + 4 * ti);
            *(float4*)&ws[m][4 * ti] = wv;
        }
        __syncthreads();
#pragma unroll 16
        for (int k = 0; k < 64; ++k) {
            float4 xv = *(const float4*)&xt[k][4 * tj];
            float4 wv = *(const float4*)&ws[k][4 * ti];
            float xa[4] = {xv.x, xv.y, xv.z, xv.w};
            float wa[4] = {wv.x, wv.y, wv.z, wv.w};
#pragma unroll
            for (int i = 0; i < 4; ++i)
#pragma unroll
                for (int j = 0; j < 4; ++j)
                    acc[i][j] = fmaf(xa[i], wa[j], acc[i][j]);
        }
    }
#pragma unroll
    for (int i = 0; i < 4; ++i) {
        int node = node0 + 4 * tj + i;
        if (node < N_NODES) {
            float dv = dinv[node];
            float4 o = make_float4(acc[i][0] * dv, acc[i][1] * dv,
                                   acc[i][2] * dv, acc[i][3] * dv);
            *(float4*)(u + (size_t)node * D_H + 4 * ti) = o;
        }
    }
}

// ---------------- aggregation (one wave per node, 8-deep gathers) ----------

__device__ __forceinline__ float agg_gather(const float* __restrict__ u,
                                            const int* __restrict__ col,
                                            int beg, int end, int lane, float acc) {
    int e = beg;
    for (; e + 7 < end; e += 8) {                // 8 independent gathers in flight
        int s0 = col[e],     s1 = col[e + 1], s2 = col[e + 2], s3 = col[e + 3];
        int s4 = col[e + 4], s5 = col[e + 5], s6 = col[e + 6], s7 = col[e + 7];
        float v0 = u[(size_t)s0 * D_H + lane];
        float v1 = u[(size_t)s1 * D_H + lane];
        float v2 = u[(size_t)s2 * D_H + lane];
        float v3 = u[(size_t)s3 * D_H + lane];
        float v4 = u[(size_t)s4 * D_H + lane];
        float v5 = u[(size_t)s5 * D_H + lane];
        float v6 = u[(size_t)s6 * D_H + lane];
        float v7 = u[(size_t)s7 * D_H + lane];
        acc += ((v0 + v1) + (v2 + v3)) + ((v4 + v5) + (v6 + v7));
    }
    for (; e < end; ++e) acc += u[(size_t)col[e] * D_H + lane];
    return acc;
}

// agg(uin) -> +self -> *dinv -> +b -> relu -> @W (LDS-staged) -> *dinv -> uout
__global__ __launch_bounds__(256) void k_agg_x(const float* __restrict__ uin,
                                               const int* __restrict__ rowptr,
                                               const int* __restrict__ col,
                                               const float* __restrict__ dinv,
                                               const float* __restrict__ b,
                                               const float* __restrict__ W,
                                               float* __restrict__ uout) {
    __shared__ float Ws[64][64];
    int t = threadIdx.x;
    for (int i = t; i < 1024; i += 256) ((float4*)Ws)[i] = ((const float4*)W)[i];
    __syncthreads();
    int lane = t & 63;
    int node = (blockIdx.x * blockDim.x + t) >> 6;
    if (node >= N_NODES) return;
    float acc = uin[(size_t)node * D_H + lane];    // self loop
    acc = agg_gather(uin, col, rowptr[node], rowptr[node + 1], lane, acc);
    float dv = dinv[node];
    float hv = fmaxf(acc * dv + b[lane], 0.0f);
    float o = 0.0f;
#pragma unroll
    for (int kk = 0; kk < 64; ++kk)
        o = fmaf(__shfl(hv, kk, 64), Ws[kk][lane], o);
    uout[(size_t)node * D_H + lane] = o * dv;
}

// agg(uin) -> +self -> *dinv -> +b3 -> dot(Wl) -> val   (layer 3 + head)
__global__ __launch_bounds__(256) void k_agg_dot(const float* __restrict__ uin,
                                                 const int* __restrict__ rowptr,
                                                 const int* __restrict__ col,
                                                 const float* __restrict__ dinv,
                                                 const float* __restrict__ b,
                                                 const float* __restrict__ Wl,
                                                 float* __restrict__ val) {
    int lane = threadIdx.x & 63;
    int node = (blockIdx.x * blockDim.x + threadIdx.x) >> 6;
    if (node >= N_NODES) return;
    float acc = uin[(size_t)node * D_H + lane];    // self loop
    acc = agg_gather(uin, col, rowptr[node], rowptr[node + 1], lane, acc);
    acc = acc * dinv[node] + b[lane];
    float v = acc * Wl[lane];
#pragma unroll
    for (int m = 32; m > 0; m >>= 1) v += __shfl_xor(v, m, 64);
    if (lane == 0) val[node] = v;
}

// one block per graph: batch is sorted, binary-search the segment, reduce.
__global__ __launch_bounds__(256) void k_gpool(const float* __restrict__ val,
                                               const int* __restrict__ batch,
                                               const float* __restrict__ bl,
                                               float* __restrict__ out) {
    int g = blockIdx.x;
    int l = 0, r = N_NODES;
    while (l < r) { int m = (l + r) >> 1; if (batch[m] < g) l = m + 1; else r = m; }
    int lo = l;
    r = N_NODES;
    while (l < r) { int m = (l + r) >> 1; if (batch[m] < g + 1) l = m + 1; else r = m; }
    int hi = l;
    float s = 0.0f;
    for (int i = lo + threadIdx.x; i < hi; i += 256) s += val[i];
#pragma unroll
    for (int m = 32; m > 0; m >>= 1) s += __shfl_xor(s, m, 64);
    __shared__ float red[4];
    int wid = threadIdx.x >> 6, lane = threadIdx.x & 63;
    if (lane == 0) red[wid] = s;
    __syncthreads();
    if (threadIdx.x == 0) {
        float t = red[0] + red[1] + red[2] + red[3];
        out[g] = t / fmaxf((float)(hi - lo), 1.0f) + bl[0];
    }
}

// ---------------- launch ----------------

extern "C" void kernel_launch(void* const* d_in, const int* in_sizes, int n_in,
                              void* d_out, int out_size, void* d_ws, size_t ws_size,
                              hipStream_t stream) {
    const float* x   = (const float*)d_in[0];
    const int*   ei  = (const int*)d_in[1];
    const int*   bat = (const int*)d_in[2];
    const float* W1  = (const float*)d_in[3];
    const float* b1  = (const float*)d_in[4];
    const float* W2  = (const float*)d_in[5];
    const float* b2  = (const float*)d_in[6];
    const float* W3  = (const float*)d_in[7];
    const float* b3  = (const float*)d_in[8];
    const float* Wl  = (const float*)d_in[9];
    const float* bl  = (const float*)d_in[10];
    float* out = (float*)d_out;

    char* p = (char*)d_ws;
    auto alloc = [&](size_t bytes) -> void* {
        void* r = (void*)p;
        p += (bytes + 255) & ~(size_t)255;
        return r;
    };
    int*   ghist   = (int*)alloc((size_t)NBIN * 4);
    int*   binbase = (int*)alloc((size_t)(NBIN + 1) * 4);
    int*   gcur    = (int*)alloc((size_t)NBIN * 4);
    int*   rowptr  = (int*)alloc((size_t)(N_NODES + 1) * 4);
    float* dinv    = (float*)alloc((size_t)N_NODES * 4);
    int*   colb    = (int*)alloc((size_t)N_EDGES * 4);
    int*   ebuf    = (int*)alloc((size_t)N_EDGES * 4);
    float* u1      = (float*)alloc((size_t)N_NODES * D_H * 4);
    float* u2      = (float*)alloc((size_t)N_NODES * D_H * 4);
    float* val     = (float*)alloc((size_t)N_NODES * 4);

    hipMemsetAsync(ghist, 0, (size_t)NBIN * 4, stream);

    const int* srcp = ei;
    const int* dstp = ei + N_EDGES;

    int wbl = (N_NODES * 64 + 255) / 256;           // one wave per node
    int gbl = (N_NODES + 63) / 64;

    // CSR build
    k_hist<<<HIST_BLOCKS, 256, 0, stream>>>(dstp, ghist);
    k_scanbins<<<1, 512, 0, stream>>>(ghist, binbase, gcur, rowptr);
    k_part<<<PART_BLOCKS, 256, 0, stream>>>(srcp, dstp, gcur, ebuf);
    k_sortbin<<<NBIN, 256, 0, stream>>>(binbase, ebuf, colb, rowptr, dinv);

    // layer 1 transform: 320 -> 64
    k_gemm<D_IN><<<gbl, 256, 0, stream>>>(x, W1, dinv, u1);
    // agg1 + relu + @W2 fused
    k_agg_x<<<wbl, 256, 0, stream>>>(u1, rowptr, colb, dinv, b1, W2, u2);
    // agg2 + relu + @W3 fused
    k_agg_x<<<wbl, 256, 0, stream>>>(u2, rowptr, colb, dinv, b2, W3, u1);
    // agg3 + head dot
    k_agg_dot<<<wbl, 256, 0, stream>>>(u1, rowptr, colb, dinv, b3, Wl, val);

    // pooling
    k_gpool<<<N_GRAPHS, 256, 0, stream>>>(val, bat, bl, out);
}

// Round 9
// 572.468 us; speedup vs baseline: 6.7859x; 1.0783x over previous
//
#include <hip/hip_runtime.h>
#include <hip/hip_bf16.h>

#define N_NODES 100000
#define N_EDGES 3200000
#define N_GRAPHS 256
#define D_IN 320
#define D_H 64

#define NBIN 391                    // ceil(N_NODES / 256) bins of 256 dst nodes
#define BIN_CAP 12288               // mean bin load 8186, sigma~90 -> +45 sigma
#define HIST_BLOCKS 256
#define HIST_CHUNK ((N_EDGES + HIST_BLOCKS - 1) / HIST_BLOCKS)
#define PART_BLOCKS 200
#define PART_CHUNK ((N_EDGES + PART_BLOCKS - 1) / PART_BLOCKS)   // 16000

// ---------------- CSR build (block-private chunk partition) ----------------

__global__ __launch_bounds__(256) void k_hist(const int* __restrict__ dst,
                                              int* __restrict__ ghist) {
    __shared__ int lh[NBIN];
    for (int i = threadIdx.x; i < NBIN; i += 256) lh[i] = 0;
    __syncthreads();
    int beg = blockIdx.x * HIST_CHUNK;
    int end = min(beg + HIST_CHUNK, N_EDGES);
    for (int e = beg + threadIdx.x; e < end; e += 256)
        atomicAdd(&lh[dst[e] >> 8], 1);
    __syncthreads();
    for (int i = threadIdx.x; i < NBIN; i += 256)
        if (lh[i]) atomicAdd(&ghist[i], lh[i]);
}

__global__ __launch_bounds__(512) void k_scanbins(const int* __restrict__ ghist,
                                                  int* __restrict__ binbase,
                                                  int* __restrict__ gcur,
                                                  int* __restrict__ rowptr) {
    __shared__ int sa[512], sb[512];
    int t = threadIdx.x;
    int v = (t < NBIN) ? ghist[t] : 0;
    sa[t] = v;
    __syncthreads();
    int* in = sa; int* out = sb;
    for (int off = 1; off < 512; off <<= 1) {
        out[t] = in[t] + (t >= off ? in[t - off] : 0);
        __syncthreads();
        int* tmp = in; in = out; out = tmp;
    }
    int excl = in[t] - v;
    if (t < NBIN) { binbase[t] = excl; gcur[t] = excl; }
    if (t == 511) { binbase[NBIN] = in[511]; rowptr[N_NODES] = in[511]; }
}

// partition edges into 391 bins; each block reserves a private contiguous
// chunk per bin (one global atomic per (block,bin)) -> every ebuf cacheline
// is written by exactly one block, once.
__global__ __launch_bounds__(256) void k_part(const int* __restrict__ src,
                                              const int* __restrict__ dst,
                                              int* __restrict__ gcur,
                                              int* __restrict__ ebuf) {
    __shared__ int lh[NBIN], gb[NBIN], cur[NBIN];
    for (int i = threadIdx.x; i < NBIN; i += 256) { lh[i] = 0; cur[i] = 0; }
    __syncthreads();
    int beg = blockIdx.x * PART_CHUNK;
    int end = min(beg + PART_CHUNK, N_EDGES);
    for (int e = beg + threadIdx.x; e < end; e += 256)
        atomicAdd(&lh[dst[e] >> 8], 1);
    __syncthreads();
    for (int i = threadIdx.x; i < NBIN; i += 256)
        gb[i] = lh[i] ? atomicAdd(&gcur[i], lh[i]) : 0;
    __syncthreads();
    for (int e = beg + threadIdx.x; e < end; e += 256) {
        int d = dst[e], s = src[e];
        int bin = d >> 8;
        int r = atomicAdd(&cur[bin], 1);
        ebuf[gb[bin] + r] = ((d & 255) << 17) | s;   // dst-low-8 | src(17b)
    }
}

// one block per bin: counting-sort by (dst_local, src_bucket). Node lists
// stay contiguous (rowptr valid for k_agg), but each list is internally
// sorted by 8K-src-bucket -> all waves sweep src low->high together.
__global__ __launch_bounds__(256) void k_sortbin(const int* __restrict__ binbase,
                                                 const int* __restrict__ ebuf,
                                                 int* __restrict__ col,
                                                 int* __restrict__ rowptr,
                                                 float* __restrict__ dinv) {
    __shared__ int hc[4096], sc[4096];
    __shared__ int sa[256], sb[256];
    __shared__ int scol[BIN_CAP];
    int b = blockIdx.x, t = threadIdx.x;
    int d0 = b << 8;
    int e0 = binbase[b], e1 = binbase[b + 1];
    for (int i = t; i < 4096; i += 256) hc[i] = 0;
    __syncthreads();
    for (int i = e0 + t; i < e1; i += 256) {
        int pk = ebuf[i];
        int dl = pk >> 17, s = pk & 0x1FFFF;
        atomicAdd(&hc[(dl << 4) | (s >> 13)], 1);   // key = dst_local*16 + bucket
    }
    __syncthreads();
    // thread t owns keys [t*16, t*16+16) == node (d0+t)'s 13 buckets
    int loc[16]; int sum = 0;
#pragma unroll
    for (int q = 0; q < 16; ++q) { loc[q] = sum; sum += hc[t * 16 + q]; }
    sa[t] = sum;
    __syncthreads();
    int* in = sa; int* out = sb;
    for (int o = 1; o < 256; o <<= 1) {
        out[t] = in[t] + (t >= o ? in[t - o] : 0);
        __syncthreads();
        int* tm = in; in = out; out = tm;
    }
    int tbase = in[t] - sum;           // exclusive prefix of node degrees
#pragma unroll
    for (int q = 0; q < 16; ++q) sc[t * 16 + q] = tbase + loc[q];
    int node = d0 + t;
    if (node < N_NODES) {
        rowptr[node] = e0 + tbase;
        dinv[node] = rsqrtf((float)(sum + 1));   // +1 self loop
    }
    __syncthreads();
    for (int i = e0 + t; i < e1; i += 256) {
        int pk = ebuf[i];
        int dl = pk >> 17, s = pk & 0x1FFFF;
        int p = atomicAdd(&sc[(dl << 4) | (s >> 13)], 1);
        if (p < BIN_CAP) scol[p] = s;
    }
    __syncthreads();
    int n = e1 - e0;
    for (int i = t; i < n; i += 256) col[e0 + i] = scol[i];
}

// ---------------- tiled GEMM transform ----------------
// u[node][f] = (A[node,:] @ W)[f] * dinv[node]
template<int K>
__global__ __launch_bounds__(256) void k_gemm(const float* __restrict__ A,
                                              const float* __restrict__ W,
                                              const float* __restrict__ dinv,
                                              float* __restrict__ u) {
    __shared__ __align__(16) float xt[64][68];
    __shared__ __align__(16) float ws[64][68];
    int t = threadIdx.x;
    int ti = t & 15;
    int tj = t >> 4;
    int node0 = blockIdx.x * 64;
    float acc[4][4] = {{0.f}};

    for (int kc = 0; kc < K; kc += 64) {
        if (kc) __syncthreads();
#pragma unroll
        for (int p = 0; p < 4; ++p) {
            int m = tj + 16 * p;
            int node = node0 + m;
            if (node >= N_NODES) node = N_NODES - 1;
            float4 v = *(const float4*)(A + (size_t)node * K + kc + 4 * ti);
            xt[4 * ti + 0][m] = v.x;
            xt[4 * ti + 1][m] = v.y;
            xt[4 * ti + 2][m] = v.z;
            xt[4 * ti + 3][m] = v.w;
            float4 wv = *(const float4*)(W + (size_t)(kc + m) * D_H + 4 * ti);
            *(float4*)&ws[m][4 * ti] = wv;
        }
        __syncthreads();
#pragma unroll 16
        for (int k = 0; k < 64; ++k) {
            float4 xv = *(const float4*)&xt[k][4 * tj];
            float4 wv = *(const float4*)&ws[k][4 * ti];
            float xa[4] = {xv.x, xv.y, xv.z, xv.w};
            float wa[4] = {wv.x, wv.y, wv.z, wv.w};
#pragma unroll
            for (int i = 0; i < 4; ++i)
#pragma unroll
                for (int j = 0; j < 4; ++j)
                    acc[i][j] = fmaf(xa[i], wa[j], acc[i][j]);
        }
    }
#pragma unroll
    for (int i = 0; i < 4; ++i) {
        int node = node0 + 4 * tj + i;
        if (node < N_NODES) {
            float dv = dinv[node];
            float4 o = make_float4(acc[i][0] * dv, acc[i][1] * dv,
                                   acc[i][2] * dv, acc[i][3] * dv);
            *(float4*)(u + (size_t)node * D_H + 4 * ti) = o;
        }
    }
}

// ---------------- aggregation (one wave per node, 8-deep gathers) ----------

__device__ __forceinline__ float agg_gather(const float* __restrict__ u,
                                            const int* __restrict__ col,
                                            int beg, int end, int lane, float acc) {
    int e = beg;
    for (; e + 7 < end; e += 8) {                // 8 independent gathers in flight
        int s0 = col[e],     s1 = col[e + 1], s2 = col[e + 2], s3 = col[e + 3];
        int s4 = col[e + 4], s5 = col[e + 5], s6 = col[e + 6], s7 = col[e + 7];
        float v0 = u[(size_t)s0 * D_H + lane];
        float v1 = u[(size_t)s1 * D_H + lane];
        float v2 = u[(size_t)s2 * D_H + lane];
        float v3 = u[(size_t)s3 * D_H + lane];
        float v4 = u[(size_t)s4 * D_H + lane];
        float v5 = u[(size_t)s5 * D_H + lane];
        float v6 = u[(size_t)s6 * D_H + lane];
        float v7 = u[(size_t)s7 * D_H + lane];
        acc += ((v0 + v1) + (v2 + v3)) + ((v4 + v5) + (v6 + v7));
    }
    for (; e < end; ++e) acc += u[(size_t)col[e] * D_H + lane];
    return acc;
}

// h[i] = relu( dinv[i] * (sum_{src in N(i)} u[src] + u[i]) + b )
__global__ __launch_bounds__(256) void k_agg(const float* __restrict__ u,
                                             const int* __restrict__ rowptr,
                                             const int* __restrict__ col,
                                             const float* __restrict__ dinv,
                                             const float* __restrict__ b,
                                             float* __restrict__ h) {
    int lane = threadIdx.x & 63;
    int node = (blockIdx.x * blockDim.x + threadIdx.x) >> 6;
    if (node >= N_NODES) return;
    float acc = u[(size_t)node * D_H + lane];    // self loop
    acc = agg_gather(u, col, rowptr[node], rowptr[node + 1], lane, acc);
    acc = acc * dinv[node] + b[lane];
    h[(size_t)node * D_H + lane] = fmaxf(acc, 0.0f);
}

// layer 3 fused with the linear head: val[i] = dot(agg_row + b3, Wl)
__global__ __launch_bounds__(256) void k_agg_dot(const float* __restrict__ uin,
                                                 const int* __restrict__ rowptr,
                                                 const int* __restrict__ col,
                                                 const float* __restrict__ dinv,
                                                 const float* __restrict__ b,
                                                 const float* __restrict__ Wl,
                                                 float* __restrict__ val) {
    int lane = threadIdx.x & 63;
    int node = (blockIdx.x * blockDim.x + threadIdx.x) >> 6;
    if (node >= N_NODES) return;
    float acc = uin[(size_t)node * D_H + lane];    // self loop
    acc = agg_gather(uin, col, rowptr[node], rowptr[node + 1], lane, acc);
    acc = acc * dinv[node] + b[lane];
    float v = acc * Wl[lane];
#pragma unroll
    for (int m = 32; m > 0; m >>= 1) v += __shfl_xor(v, m, 64);
    if (lane == 0) val[node] = v;
}

// one block per graph: batch is sorted, binary-search the segment, reduce.
__global__ __launch_bounds__(256) void k_gpool(const float* __restrict__ val,
                                               const int* __restrict__ batch,
                                               const float* __restrict__ bl,
                                               float* __restrict__ out) {
    int g = blockIdx.x;
    int l = 0, r = N_NODES;
    while (l < r) { int m = (l + r) >> 1; if (batch[m] < g) l = m + 1; else r = m; }
    int lo = l;
    r = N_NODES;
    while (l < r) { int m = (l + r) >> 1; if (batch[m] < g + 1) l = m + 1; else r = m; }
    int hi = l;
    float s = 0.0f;
    for (int i = lo + threadIdx.x; i < hi; i += 256) s += val[i];
#pragma unroll
    for (int m = 32; m > 0; m >>= 1) s += __shfl_xor(s, m, 64);
    __shared__ float red[4];
    int wid = threadIdx.x >> 6, lane = threadIdx.x & 63;
    if (lane == 0) red[wid] = s;
    __syncthreads();
    if (threadIdx.x == 0) {
        float t = red[0] + red[1] + red[2] + red[3];
        out[g] = t / fmaxf((float)(hi - lo), 1.0f) + bl[0];
    }
}

// ---------------- launch ----------------

extern "C" void kernel_launch(void* const* d_in, const int* in_sizes, int n_in,
                              void* d_out, int out_size, void* d_ws, size_t ws_size,
                              hipStream_t stream) {
    const float* x   = (const float*)d_in[0];
    const int*   ei  = (const int*)d_in[1];
    const int*   bat = (const int*)d_in[2];
    const float* W1  = (const float*)d_in[3];
    const float* b1  = (const float*)d_in[4];
    const float* W2  = (const float*)d_in[5];
    const float* b2  = (const float*)d_in[6];
    const float* W3  = (const float*)d_in[7];
    const float* b3  = (const float*)d_in[8];
    const float* Wl  = (const float*)d_in[9];
    const float* bl  = (const float*)d_in[10];
    float* out = (float*)d_out;

    char* p = (char*)d_ws;
    auto alloc = [&](size_t bytes) -> void* {
        void* r = (void*)p;
        p += (bytes + 255) & ~(size_t)255;
        return r;
    };
    int*   ghist   = (int*)alloc((size_t)NBIN * 4);
    int*   binbase = (int*)alloc((size_t)(NBIN + 1) * 4);
    int*   gcur    = (int*)alloc((size_t)NBIN * 4);
    int*   rowptr  = (int*)alloc((size_t)(N_NODES + 1) * 4);
    float* dinv    = (float*)alloc((size_t)N_NODES * 4);
    int*   colb    = (int*)alloc((size_t)N_EDGES * 4);
    int*   ebuf    = (int*)alloc((size_t)N_EDGES * 4);
    float* u1      = (float*)alloc((size_t)N_NODES * D_H * 4);
    float* u2      = (float*)alloc((size_t)N_NODES * D_H * 4);
    float* h       = (float*)alloc((size_t)N_NODES * D_H * 4);
    float* val     = (float*)alloc((size_t)N_NODES * 4);

    hipMemsetAsync(ghist, 0, (size_t)NBIN * 4, stream);

    const int* srcp = ei;
    const int* dstp = ei + N_EDGES;

    int wbl = (N_NODES * 64 + 255) / 256;           // one wave per node
    int gbl = (N_NODES + 63) / 64;

    // CSR build (src-bucket-sorted node lists)
    k_hist<<<HIST_BLOCKS, 256, 0, stream>>>(dstp, ghist);
    k_scanbins<<<1, 512, 0, stream>>>(ghist, binbase, gcur, rowptr);
    k_part<<<PART_BLOCKS, 256, 0, stream>>>(srcp, dstp, gcur, ebuf);
    k_sortbin<<<NBIN, 256, 0, stream>>>(binbase, ebuf, colb, rowptr, dinv);

    // layer 1: 320 -> 64
    k_gemm<D_IN><<<gbl, 256, 0, stream>>>(x, W1, dinv, u1);
    k_agg<<<wbl, 256, 0, stream>>>(u1, rowptr, colb, dinv, b1, h);
    // layer 2: 64 -> 64
    k_gemm<D_H><<<gbl, 256, 0, stream>>>(h, W2, dinv, u2);
    k_agg<<<wbl, 256, 0, stream>>>(u2, rowptr, colb, dinv, b2, h);
    // layer 3: 64 -> 64, fused with linear head dot
    k_gemm<D_H><<<gbl, 256, 0, stream>>>(h, W3, dinv, u1);
    k_agg_dot<<<wbl, 256, 0, stream>>>(u1, rowptr, colb, dinv, b3, Wl, val);

    // pooling
    k_gpool<<<N_GRAPHS, 256, 0, stream>>>(val, bat, bl, out);
}